// Round 13
// baseline (84.666 us; speedup 1.0000x reference)
//
#include <hip/hip_runtime.h>

#define TLEN 1461
#define REPS 4
#define L2E      1.44269504088896340736f
#define TWO_L2E  2.88539008177792681472f
#define NL2E10  -14.4269504088896341f

typedef __bf16 bf16x8 __attribute__((ext_vector_type(8)));
typedef float f32x16 __attribute__((ext_vector_type(16)));

union FragU { unsigned u[4]; bf16x8 f; };

__device__ __forceinline__ unsigned cvt_pk_bf16(float lo, float hi) {
    unsigned r;
    asm("v_cvt_pk_bf16_f32 %0, %1, %2" : "=v"(r) : "v"(lo), "v"(hi));
    return r;
}
__device__ __forceinline__ void plswap(unsigned &a, unsigned &b) {
    asm("v_permlane32_swap_b32 %0, %1" : "+v"(a), "+v"(b));
}
__device__ __forceinline__ float plswap_add(float a, float b) {
    unsigned ua = __float_as_uint(a), ub = __float_as_uint(b);
    plswap(ua, ub);
    return __uint_as_float(ua) + __uint_as_float(ub);
}

// 4 pre-activations y=2*log2e*x -> tanh, ONE rcp per 4 (clamp +-30)
__device__ __forceinline__ void quad_tanh_pack(float y0, float y1, float y2, float y3,
                                               unsigned &wlo, unsigned &whi) {
    y0 = fminf(fmaxf(y0, -30.0f), 30.0f);
    y1 = fminf(fmaxf(y1, -30.0f), 30.0f);
    y2 = fminf(fmaxf(y2, -30.0f), 30.0f);
    y3 = fminf(fmaxf(y3, -30.0f), 30.0f);
    float d0 = 1.0f + __builtin_amdgcn_exp2f(y0);
    float d1 = 1.0f + __builtin_amdgcn_exp2f(y1);
    float d2 = 1.0f + __builtin_amdgcn_exp2f(y2);
    float d3 = 1.0f + __builtin_amdgcn_exp2f(y3);
    float Pab = d0 * d1, Pcd = d2 * d3;
    float R = __builtin_amdgcn_rcpf(Pab * Pcd);
    float RPcd = Pcd * R;   // = 1/(d0 d1)
    float RPab = Pab * R;   // = 1/(d2 d3)
    float t0 = d1 * RPcd, t1 = d0 * RPcd;
    float t2 = d3 * RPab, t3 = d2 * RPab;
    float h0 = fmaf(-2.0f, t0, 1.0f), h1 = fmaf(-2.0f, t1, 1.0f);
    float h2 = fmaf(-2.0f, t2, 1.0f), h3 = fmaf(-2.0f, t3, 1.0f);
    wlo = cvt_pk_bf16(h0, h1);
    whi = cvt_pk_bf16(h2, h3);
}

// sum_i w[i]*sigma(y[i]) with ONE rcp; no clamp (|y|<=~25 here)
__device__ __forceinline__ float quad_wsum_raw(float y0, float y1, float y2, float y3,
                                               float w0, float w1, float w2, float w3) {
    float d0 = 1.0f + __builtin_amdgcn_exp2f(y0);
    float d1 = 1.0f + __builtin_amdgcn_exp2f(y1);
    float d2 = 1.0f + __builtin_amdgcn_exp2f(y2);
    float d3 = 1.0f + __builtin_amdgcn_exp2f(y3);
    float Pab = d0 * d1, Pcd = d2 * d3;
    float R = __builtin_amdgcn_rcpf(Pab * Pcd);
    float N1 = fmaf(w1, d0, w0 * d1);
    float N2 = fmaf(w3, d2, w2 * d3);
    return fmaf(N2, Pab, N1 * Pcd) * R;
}

// layer2 MFMA + sigma-folded dot, sequential blocks (16 C regs live).
template <int BASE>
__device__ __forceinline__ float tail_seq(const FragU a2,
    const float* __restrict__ b2, const float* __restrict__ w3,
    float pinit, bool hi, const FragU ba, const FragU bb)
{
    float w3s[8];
#pragma unroll
    for (int r = 0; r < 8; ++r) {
        const int j0 = (r & 3) + 8 * (r >> 2);
        w3s[r] = hi ? w3[j0 + 4] : w3[j0];
    }
    float p0, p1;
    {
        f32x16 c;
#pragma unroll
        for (int r = 0; r < 8; ++r) {
            const int j0 = (r & 3) + 8 * (r >> 2);
            c[BASE + r] = TWO_L2E * (hi ? b2[j0 + 4] : b2[j0]);
        }
        c = __builtin_amdgcn_mfma_f32_32x32x16_bf16(a2.f, ba.f, c, 0, 0, 0);
        float q = quad_wsum_raw(c[BASE + 0], c[BASE + 1], c[BASE + 2], c[BASE + 3],
                                w3s[0], w3s[1], w3s[2], w3s[3])
                + quad_wsum_raw(c[BASE + 4], c[BASE + 5], c[BASE + 6], c[BASE + 7],
                                w3s[4], w3s[5], w3s[6], w3s[7]);
        p0 = fmaf(-2.0f * L2E, q, pinit);
    }
    {
        f32x16 c;
#pragma unroll
        for (int r = 0; r < 8; ++r) {
            const int j0 = (r & 3) + 8 * (r >> 2);
            c[BASE + r] = TWO_L2E * (hi ? b2[j0 + 4] : b2[j0]);
        }
        c = __builtin_amdgcn_mfma_f32_32x32x16_bf16(a2.f, bb.f, c, 0, 0, 0);
        float q = quad_wsum_raw(c[BASE + 0], c[BASE + 1], c[BASE + 2], c[BASE + 3],
                                w3s[0], w3s[1], w3s[2], w3s[3])
                + quad_wsum_raw(c[BASE + 4], c[BASE + 5], c[BASE + 6], c[BASE + 7],
                                w3s[4], w3s[5], w3s[6], w3s[7]);
        p1 = fmaf(-2.0f * L2E, q, pinit);
    }
    return plswap_add(p0, p1);
}

// DIAGNOSTIC build: per-sample pipeline repeated REPS times with an asm
// barrier forcing full recompute (incl. gathers). Output values identical
// to single-pass; marginal-pass time + steady-state counters identify the
// binding regime (issue vs gather vs cache-cold).
__global__ __launch_bounds__(256, 8) void hydro_kernel(
    const float* __restrict__ g_t,
    const float* __restrict__ g_S,
    const float* __restrict__ g_precp,
    const float* __restrict__ g_temp,
    const float* __restrict__ g_lday,
    const float* __restrict__ g_ew1, const float* __restrict__ g_eb1,
    const float* __restrict__ g_ew2, const float* __restrict__ g_eb2,
    const float* __restrict__ g_ew3, const float* __restrict__ g_eb3,
    const float* __restrict__ g_qw1, const float* __restrict__ g_qb1,
    const float* __restrict__ g_qw2, const float* __restrict__ g_qb2,
    const float* __restrict__ g_qw3, const float* __restrict__ g_qb3,
    const float* __restrict__ g_Df, const float* __restrict__ g_Tmax,
    const float* __restrict__ g_Tmin,
    float* __restrict__ g_out, int B)
{
    const int tx = threadIdx.x;
    const int lane = tx & 63;
    const int m  = lane & 31;
    const bool hi = (lane >> 5) != 0;

    // one-time setup (outside rep loop, as in the production kernel)
    FragU a2;
    {
        const float* wsrc = (m < 16) ? g_ew2 : g_qw2;
        const int mm = m & 15;
        const int kg8 = hi ? 8 : 0;
#pragma unroll
        for (int p = 0; p < 4; ++p) {
            const int k0 = kg8 + 2 * p, k1 = k0 + 1;
            a2.u[p] = cvt_pk_bf16(TWO_L2E * wsrc[k0 * 16 + mm],
                                  TWO_L2E * wsrc[k1 * 16 + mm]);
        }
    }
    float slo_e = 0.0f, shi_e = 0.0f, slo_q = 0.0f, shi_q = 0.0f;
#pragma unroll
    for (int r = 0; r < 8; ++r) {
        const int j0 = (r & 3) + 8 * (r >> 2);
        slo_e += g_ew3[j0]; shi_e += g_ew3[j0 + 4];
        slo_q += g_qw3[j0]; shi_q += g_qw3[j0 + 4];
    }
    const float pinit_e = L2E * fmaf(0.5f, g_eb3[0], hi ? shi_e : slo_e);
    const float pinit_q = L2E * fmaf(0.5f, g_qb3[0], hi ? shi_q : slo_q);

    const float Df   = fminf(fmaxf(g_Df[0],   0.01f), 5.0f);
    const float Tmax = fminf(fmaxf(g_Tmax[0], 0.0f),  3.0f);
    const float Tmin = fminf(fmaxf(g_Tmin[0], -3.0f), 0.0f);

    const int i = blockIdx.x * 256 + tx;
    const int ic = (i < B) ? i : (B - 1);

    float tv = g_t[ic];
    float2 Sv = reinterpret_cast<const float2*>(g_S)[ic];

#pragma unroll 1
    for (int rep = 0; rep < REPS; ++rep) {
        // anti-hoist barrier: compiler must treat inputs as new each pass
        asm volatile("" : "+v"(tv), "+v"(Sv.x), "+v"(Sv.y));
        const float S_snow = Sv.x, S_water = Sv.y;

        int idx = (int)tv;
        idx = max(0, min(idx, TLEN - 2));
        const float fr = tv - (float)idx;
        const float p0v = g_precp[idx], p1v = g_precp[idx + 1];
        const float t0v = g_temp[idx],  t1v = g_temp[idx + 1];
        const float l0v = g_lday[idx],  l1v = g_lday[idx + 1];
        const float precp = fmaf(fr, p1v - p0v, p0v);
        const float temp  = fmaf(fr, t1v - t0v, t0v);
        const float lday  = fmaf(fr, l1v - l0v, l0v);

        float ETs;
        {
            unsigned w[8];
#pragma unroll
            for (int j4 = 0; j4 < 4; ++j4) {
                float4 b4 = *reinterpret_cast<const float4*>(&g_eb1[j4 * 4]);
                float4 w0 = *reinterpret_cast<const float4*>(&g_ew1[0 * 16 + j4 * 4]);
                float4 w1 = *reinterpret_cast<const float4*>(&g_ew1[1 * 16 + j4 * 4]);
                float4 w2 = *reinterpret_cast<const float4*>(&g_ew1[2 * 16 + j4 * 4]);
                float y0 = TWO_L2E * fmaf(temp, w2.x, fmaf(S_water, w1.x, fmaf(S_snow, w0.x, b4.x)));
                float y1 = TWO_L2E * fmaf(temp, w2.y, fmaf(S_water, w1.y, fmaf(S_snow, w0.y, b4.y)));
                float y2 = TWO_L2E * fmaf(temp, w2.z, fmaf(S_water, w1.z, fmaf(S_snow, w0.z, b4.z)));
                float y3 = TWO_L2E * fmaf(temp, w2.w, fmaf(S_water, w1.w, fmaf(S_snow, w0.w, b4.w)));
                unsigned wl, wh;
                quad_tanh_pack(y0, y1, y2, y3, wl, wh);
                w[2 * j4]     = wl;
                w[2 * j4 + 1] = wh;
            }
            FragU ba, bb;
#pragma unroll
            for (int p = 0; p < 4; ++p) {
                unsigned a = w[p], b = w[p + 4];
                plswap(a, b);
                ba.u[p] = a; bb.u[p] = b;
            }
            ETs = tail_seq<0>(a2, g_eb2, g_ew3, pinit_e, hi, ba, bb);
        }

        float Qs;
        {
            unsigned w[8];
#pragma unroll
            for (int j4 = 0; j4 < 4; ++j4) {
                float4 b4 = *reinterpret_cast<const float4*>(&g_qb1[j4 * 4]);
                float4 w0 = *reinterpret_cast<const float4*>(&g_qw1[0 * 16 + j4 * 4]);
                float4 w1 = *reinterpret_cast<const float4*>(&g_qw1[1 * 16 + j4 * 4]);
                float y0 = TWO_L2E * fmaf(precp, w1.x, fmaf(S_water, w0.x, b4.x));
                float y1 = TWO_L2E * fmaf(precp, w1.y, fmaf(S_water, w0.y, b4.y));
                float y2 = TWO_L2E * fmaf(precp, w1.z, fmaf(S_water, w0.z, b4.z));
                float y3 = TWO_L2E * fmaf(precp, w1.w, fmaf(S_water, w0.w, b4.w));
                unsigned wl, wh;
                quad_tanh_pack(y0, y1, y2, y3, wl, wh);
                w[2 * j4]     = wl;
                w[2 * j4 + 1] = wh;
            }
            FragU ba, bb;
#pragma unroll
            for (int p = 0; p < 4; ++p) {
                unsigned a = w[p], b = w[p + 4];
                plswap(a, b);
                ba.u[p] = a; bb.u[p] = b;
            }
            Qs = tail_seq<8>(a2, g_qb2, g_qw3, pinit_q, hi, ba, bb);
        }

        float ya = fminf(fmaxf(NL2E10 * S_water,       -31.0f), 31.0f);
        float yb = fminf(fmaxf(NL2E10 * (temp - Tmin), -31.0f), 31.0f);
        float yc = fminf(fmaxf(NL2E10 * (temp - Tmax), -31.0f), 31.0f);
        float yd = fminf(fmaxf(NL2E10 * S_snow,        -31.0f), 31.0f);
        float da = 1.0f + __builtin_amdgcn_exp2f(ya);
        float db = 1.0f + __builtin_amdgcn_exp2f(yb);
        float dc = 1.0f + __builtin_amdgcn_exp2f(yc);
        float dd = 1.0f + __builtin_amdgcn_exp2f(yd);
        float Pab = da * db, Pcd = dc * dd;
        float R = __builtin_amdgcn_rcpf(Pab * Pcd);
        float RPcd = Pcd * R, RPab = Pab * R;
        const float sw_step = db * RPcd;
        const float sp      = da * RPcd;
        const float st_tmax = dd * RPab;
        const float st_snow = dc * RPab;

        const float melt = st_tmax * st_snow * fminf(S_snow, Df * (temp - Tmax));
        const float dS1 = (1.0f - sp) * precp - melt;
        const float dS2 = sp * precp + melt
                        - sw_step * fmaf(lday, __builtin_amdgcn_exp2f(ETs),
                                         __builtin_amdgcn_exp2f(Qs));

        if (i < B) {
            // volatile per-component stores: keep one store per rep alive
            volatile float* vo = (volatile float*)g_out + 2 * (size_t)i;
            vo[0] = dS1;
            vo[1] = dS2;
        }
    }
}

extern "C" void kernel_launch(void* const* d_in, const int* in_sizes, int n_in,
                              void* d_out, int out_size, void* d_ws, size_t ws_size,
                              hipStream_t stream)
{
    const int B = in_sizes[0];
    const int block = 256;
    const int grid = (B + block - 1) / block;
    hipLaunchKernelGGL(hydro_kernel, dim3(grid), dim3(block), 0, stream,
        (const float*)d_in[0],  // t
        (const float*)d_in[1],  // S
        (const float*)d_in[3],  // precp_series
        (const float*)d_in[4],  // temp_series
        (const float*)d_in[5],  // lday_series
        (const float*)d_in[6],  (const float*)d_in[7],
        (const float*)d_in[8],  (const float*)d_in[9],
        (const float*)d_in[10], (const float*)d_in[11],
        (const float*)d_in[12], (const float*)d_in[13],
        (const float*)d_in[14], (const float*)d_in[15],
        (const float*)d_in[16], (const float*)d_in[17],
        (const float*)d_in[21], // Df
        (const float*)d_in[22], // Tmax
        (const float*)d_in[23], // Tmin
        (float*)d_out, B);
}

// Round 14
// 41.540 us; speedup vs baseline: 2.0381x; 2.0381x over previous
//
#include <hip/hip_runtime.h>

#define TLEN 1461
#define L2E      1.44269504088896340736f
#define TWO_L2E  2.88539008177792681472f
#define NL2E10  -14.4269504088896341f

typedef __bf16 bf16x8 __attribute__((ext_vector_type(8)));
typedef float f32x16 __attribute__((ext_vector_type(16)));

union FragU { unsigned u[4]; bf16x8 f; };

__device__ __forceinline__ unsigned cvt_pk_bf16(float lo, float hi) {
    unsigned r;
    asm("v_cvt_pk_bf16_f32 %0, %1, %2" : "=v"(r) : "v"(lo), "v"(hi));
    return r;
}
__device__ __forceinline__ void plswap(unsigned &a, unsigned &b) {
    asm("v_permlane32_swap_b32 %0, %1" : "+v"(a), "+v"(b));
}
__device__ __forceinline__ float plswap_add(float a, float b) {
    unsigned ua = __float_as_uint(a), ub = __float_as_uint(b);
    plswap(ua, ub);
    return __uint_as_float(ua) + __uint_as_float(ub);
}

// 4 pre-activations y=2*log2e*x -> tanh, ONE rcp per 4 (clamp +-30)
__device__ __forceinline__ void quad_tanh_pack(float y0, float y1, float y2, float y3,
                                               unsigned &wlo, unsigned &whi) {
    y0 = fminf(fmaxf(y0, -30.0f), 30.0f);
    y1 = fminf(fmaxf(y1, -30.0f), 30.0f);
    y2 = fminf(fmaxf(y2, -30.0f), 30.0f);
    y3 = fminf(fmaxf(y3, -30.0f), 30.0f);
    float d0 = 1.0f + __builtin_amdgcn_exp2f(y0);
    float d1 = 1.0f + __builtin_amdgcn_exp2f(y1);
    float d2 = 1.0f + __builtin_amdgcn_exp2f(y2);
    float d3 = 1.0f + __builtin_amdgcn_exp2f(y3);
    float Pab = d0 * d1, Pcd = d2 * d3;
    float R = __builtin_amdgcn_rcpf(Pab * Pcd);
    float RPcd = Pcd * R;   // = 1/(d0 d1)
    float RPab = Pab * R;   // = 1/(d2 d3)
    float t0 = d1 * RPcd, t1 = d0 * RPcd;
    float t2 = d3 * RPab, t3 = d2 * RPab;
    float h0 = fmaf(-2.0f, t0, 1.0f), h1 = fmaf(-2.0f, t1, 1.0f);
    float h2 = fmaf(-2.0f, t2, 1.0f), h3 = fmaf(-2.0f, t3, 1.0f);
    wlo = cvt_pk_bf16(h0, h1);
    whi = cvt_pk_bf16(h2, h3);
}

// sum_i w[i]*sigma(y[i]) with ONE rcp; no clamp (|y|<=~25 here)
__device__ __forceinline__ float quad_wsum_raw(float y0, float y1, float y2, float y3,
                                               float w0, float w1, float w2, float w3) {
    float d0 = 1.0f + __builtin_amdgcn_exp2f(y0);
    float d1 = 1.0f + __builtin_amdgcn_exp2f(y1);
    float d2 = 1.0f + __builtin_amdgcn_exp2f(y2);
    float d3 = 1.0f + __builtin_amdgcn_exp2f(y3);
    float Pab = d0 * d1, Pcd = d2 * d3;
    float R = __builtin_amdgcn_rcpf(Pab * Pcd);
    float N1 = fmaf(w1, d0, w0 * d1);
    float N2 = fmaf(w3, d2, w2 * d3);
    return fmaf(N2, Pab, N1 * Pcd) * R;
}

// ONE shared MLP body (layer1 3-in -> tanh16 -> layer2 MFMA -> sigma dot).
// __noinline__ : called twice -> halves the straight-line I$ footprint.
// A-fragment zero-padded (rows 16-31 = 0) so both calls use C regs 0..7.
// For 2-input MLPs pass x2 = 0 and any valid pointer for r2 (times zero).
__device__ __attribute__((noinline)) float mlp16(
    float x0, float x1, float x2,
    const float* __restrict__ r0, const float* __restrict__ r1,
    const float* __restrict__ r2, const float* __restrict__ b1,
    FragU a2, const float* __restrict__ b2, const float* __restrict__ w3,
    float pinit, bool hi)
{
    unsigned w[8];
#pragma unroll
    for (int j4 = 0; j4 < 4; ++j4) {
        float4 b4 = *reinterpret_cast<const float4*>(&b1[j4 * 4]);
        float4 w0 = *reinterpret_cast<const float4*>(&r0[j4 * 4]);
        float4 w1 = *reinterpret_cast<const float4*>(&r1[j4 * 4]);
        float4 w2 = *reinterpret_cast<const float4*>(&r2[j4 * 4]);
        float y0 = TWO_L2E * fmaf(x2, w2.x, fmaf(x1, w1.x, fmaf(x0, w0.x, b4.x)));
        float y1 = TWO_L2E * fmaf(x2, w2.y, fmaf(x1, w1.y, fmaf(x0, w0.y, b4.y)));
        float y2 = TWO_L2E * fmaf(x2, w2.z, fmaf(x1, w1.z, fmaf(x0, w0.z, b4.z)));
        float y3 = TWO_L2E * fmaf(x2, w2.w, fmaf(x1, w1.w, fmaf(x0, w0.w, b4.w)));
        unsigned wl, wh;
        quad_tanh_pack(y0, y1, y2, y3, wl, wh);
        w[2 * j4]     = wl;
        w[2 * j4 + 1] = wh;
    }
    FragU ba, bb;
#pragma unroll
    for (int p = 0; p < 4; ++p) {
        unsigned a = w[p], b = w[p + 4];
        plswap(a, b);
        ba.u[p] = a; bb.u[p] = b;
    }

    float w3s[8], jb[8];
#pragma unroll
    for (int r = 0; r < 8; ++r) {
        const int j0 = (r & 3) + 8 * (r >> 2);
        w3s[r] = hi ? w3[j0 + 4] : w3[j0];
        jb[r]  = TWO_L2E * (hi ? b2[j0 + 4] : b2[j0]);
    }
    float p0, p1;
    {
        f32x16 c;
#pragma unroll
        for (int r = 0; r < 8; ++r) c[r] = jb[r];
        c = __builtin_amdgcn_mfma_f32_32x32x16_bf16(a2.f, ba.f, c, 0, 0, 0);
        float q = quad_wsum_raw(c[0], c[1], c[2], c[3], w3s[0], w3s[1], w3s[2], w3s[3])
                + quad_wsum_raw(c[4], c[5], c[6], c[7], w3s[4], w3s[5], w3s[6], w3s[7]);
        p0 = fmaf(-2.0f * L2E, q, pinit);
    }
    {
        f32x16 c;
#pragma unroll
        for (int r = 0; r < 8; ++r) c[r] = jb[r];
        c = __builtin_amdgcn_mfma_f32_32x32x16_bf16(a2.f, bb.f, c, 0, 0, 0);
        float q = quad_wsum_raw(c[0], c[1], c[2], c[3], w3s[0], w3s[1], w3s[2], w3s[3])
                + quad_wsum_raw(c[4], c[5], c[6], c[7], w3s[4], w3s[5], w3s[6], w3s[7]);
        p1 = fmaf(-2.0f * L2E, q, pinit);
    }
    return plswap_add(p0, p1);
}

__global__ __launch_bounds__(256, 8) void hydro_kernel(
    const float* __restrict__ g_t,
    const float* __restrict__ g_S,
    const float* __restrict__ g_precp,
    const float* __restrict__ g_temp,
    const float* __restrict__ g_lday,
    const float* __restrict__ g_ew1, const float* __restrict__ g_eb1,
    const float* __restrict__ g_ew2, const float* __restrict__ g_eb2,
    const float* __restrict__ g_ew3, const float* __restrict__ g_eb3,
    const float* __restrict__ g_qw1, const float* __restrict__ g_qb1,
    const float* __restrict__ g_qw2, const float* __restrict__ g_qb2,
    const float* __restrict__ g_qw3, const float* __restrict__ g_qb3,
    const float* __restrict__ g_Df, const float* __restrict__ g_Tmax,
    const float* __restrict__ g_Tmin,
    float* __restrict__ g_out, int B)
{
    const int tx = threadIdx.x;
    const int lane = tx & 63;
    const int m  = lane & 31;
    const bool hi = (lane >> 5) != 0;

    // two zero-padded A-fragments (rows 16-31 = 0): identical tail code paths
    FragU a2e, a2q;
    {
        const int mm = m & 15;
        const int kg8 = hi ? 8 : 0;
        const float s = (m < 16) ? TWO_L2E : 0.0f;
#pragma unroll
        for (int p = 0; p < 4; ++p) {
            const int k0 = kg8 + 2 * p, k1 = k0 + 1;
            a2e.u[p] = cvt_pk_bf16(s * g_ew2[k0 * 16 + mm], s * g_ew2[k1 * 16 + mm]);
            a2q.u[p] = cvt_pk_bf16(s * g_qw2[k0 * 16 + mm], s * g_qw2[k1 * 16 + mm]);
        }
    }

    float slo_e = 0.0f, shi_e = 0.0f, slo_q = 0.0f, shi_q = 0.0f;
#pragma unroll
    for (int r = 0; r < 8; ++r) {
        const int j0 = (r & 3) + 8 * (r >> 2);
        slo_e += g_ew3[j0]; shi_e += g_ew3[j0 + 4];
        slo_q += g_qw3[j0]; shi_q += g_qw3[j0 + 4];
    }
    const float pinit_e = L2E * fmaf(0.5f, g_eb3[0], hi ? shi_e : slo_e);
    const float pinit_q = L2E * fmaf(0.5f, g_qb3[0], hi ? shi_q : slo_q);

    const float Df   = fminf(fmaxf(g_Df[0],   0.01f), 5.0f);
    const float Tmax = fminf(fmaxf(g_Tmax[0], 0.0f),  3.0f);
    const float Tmin = fminf(fmaxf(g_Tmin[0], -3.0f), 0.0f);

    const int i = blockIdx.x * 256 + tx;
    const int ic = (i < B) ? i : (B - 1);

    const float tv = g_t[ic];
    const float2 Sv = reinterpret_cast<const float2*>(g_S)[ic];
    const float S_snow = Sv.x, S_water = Sv.y;

    int idx = (int)tv;
    idx = max(0, min(idx, TLEN - 2));
    const float fr = tv - (float)idx;
    const float p0v = g_precp[idx], p1v = g_precp[idx + 1];
    const float t0v = g_temp[idx],  t1v = g_temp[idx + 1];
    const float l0v = g_lday[idx],  l1v = g_lday[idx + 1];
    const float precp = fmaf(fr, p1v - p0v, p0v);
    const float temp  = fmaf(fr, t1v - t0v, t0v);
    const float lday  = fmaf(fr, l1v - l0v, l0v);

    // ET: inputs [S_snow, S_water, temp];  Q: inputs [S_water, precp, 0]
    const float ETs = mlp16(S_snow, S_water, temp,
                            g_ew1, g_ew1 + 16, g_ew1 + 32, g_eb1,
                            a2e, g_eb2, g_ew3, pinit_e, hi);
    const float Qs  = mlp16(S_water, precp, 0.0f,
                            g_qw1, g_qw1 + 16, g_qw1, g_qb1,
                            a2q, g_qb2, g_qw3, pinit_q, hi);

    // bucket dynamics: 4 steps share ONE rcp
    float ya = fminf(fmaxf(NL2E10 * S_water,       -31.0f), 31.0f);
    float yb = fminf(fmaxf(NL2E10 * (temp - Tmin), -31.0f), 31.0f);
    float yc = fminf(fmaxf(NL2E10 * (temp - Tmax), -31.0f), 31.0f);
    float yd = fminf(fmaxf(NL2E10 * S_snow,        -31.0f), 31.0f);
    float da = 1.0f + __builtin_amdgcn_exp2f(ya);
    float db = 1.0f + __builtin_amdgcn_exp2f(yb);
    float dc = 1.0f + __builtin_amdgcn_exp2f(yc);
    float dd = 1.0f + __builtin_amdgcn_exp2f(yd);
    float Pab = da * db, Pcd = dc * dd;
    float R = __builtin_amdgcn_rcpf(Pab * Pcd);
    float RPcd = Pcd * R, RPab = Pab * R;
    const float sw_step = db * RPcd;
    const float sp      = da * RPcd;
    const float st_tmax = dd * RPab;
    const float st_snow = dc * RPab;

    const float melt = st_tmax * st_snow * fminf(S_snow, Df * (temp - Tmax));
    const float dS1 = (1.0f - sp) * precp - melt;
    const float dS2 = sp * precp + melt
                    - sw_step * fmaf(lday, __builtin_amdgcn_exp2f(ETs),
                                     __builtin_amdgcn_exp2f(Qs));

    if (i < B) {
        reinterpret_cast<float2*>(g_out)[i] = make_float2(dS1, dS2);
    }
}

extern "C" void kernel_launch(void* const* d_in, const int* in_sizes, int n_in,
                              void* d_out, int out_size, void* d_ws, size_t ws_size,
                              hipStream_t stream)
{
    const int B = in_sizes[0];
    const int block = 256;
    const int grid = (B + block - 1) / block;
    hipLaunchKernelGGL(hydro_kernel, dim3(grid), dim3(block), 0, stream,
        (const float*)d_in[0],  // t
        (const float*)d_in[1],  // S
        (const float*)d_in[3],  // precp_series
        (const float*)d_in[4],  // temp_series
        (const float*)d_in[5],  // lday_series
        (const float*)d_in[6],  (const float*)d_in[7],
        (const float*)d_in[8],  (const float*)d_in[9],
        (const float*)d_in[10], (const float*)d_in[11],
        (const float*)d_in[12], (const float*)d_in[13],
        (const float*)d_in[14], (const float*)d_in[15],
        (const float*)d_in[16], (const float*)d_in[17],
        (const float*)d_in[21], // Df
        (const float*)d_in[22], // Tmax
        (const float*)d_in[23], // Tmin
        (float*)d_out, B);
}

// Round 15
// 31.851 us; speedup vs baseline: 2.6582x; 1.3042x over previous
//
#include <hip/hip_runtime.h>

#define TLEN 1461
#define L2E      1.44269504088896340736f
#define TWO_L2E  2.88539008177792681472f
#define NL2E10  -14.4269504088896341f

typedef __bf16 bf16x8 __attribute__((ext_vector_type(8)));
typedef float f32x16 __attribute__((ext_vector_type(16)));

union FragU { unsigned u[4]; bf16x8 f; };

__device__ __forceinline__ unsigned cvt_pk_bf16(float lo, float hi) {
    unsigned r;
    asm("v_cvt_pk_bf16_f32 %0, %1, %2" : "=v"(r) : "v"(lo), "v"(hi));
    return r;
}
__device__ __forceinline__ void plswap(unsigned &a, unsigned &b) {
    asm("v_permlane32_swap_b32 %0, %1" : "+v"(a), "+v"(b));
}
__device__ __forceinline__ float plswap_add(float a, float b) {
    unsigned ua = __float_as_uint(a), ub = __float_as_uint(b);
    plswap(ua, ub);
    return __uint_as_float(ua) + __uint_as_float(ub);
}

// 4 pre-activations y=2*log2e*x -> tanh, ONE rcp per 4 (clamp +-30)
__device__ __forceinline__ void quad_tanh_pack(float y0, float y1, float y2, float y3,
                                               unsigned &wlo, unsigned &whi) {
    y0 = fminf(fmaxf(y0, -30.0f), 30.0f);
    y1 = fminf(fmaxf(y1, -30.0f), 30.0f);
    y2 = fminf(fmaxf(y2, -30.0f), 30.0f);
    y3 = fminf(fmaxf(y3, -30.0f), 30.0f);
    float d0 = 1.0f + __builtin_amdgcn_exp2f(y0);
    float d1 = 1.0f + __builtin_amdgcn_exp2f(y1);
    float d2 = 1.0f + __builtin_amdgcn_exp2f(y2);
    float d3 = 1.0f + __builtin_amdgcn_exp2f(y3);
    float Pab = d0 * d1, Pcd = d2 * d3;
    float R = __builtin_amdgcn_rcpf(Pab * Pcd);
    float RPcd = Pcd * R;   // = 1/(d0 d1)
    float RPab = Pab * R;   // = 1/(d2 d3)
    float t0 = d1 * RPcd, t1 = d0 * RPcd;
    float t2 = d3 * RPab, t3 = d2 * RPab;
    float h0 = fmaf(-2.0f, t0, 1.0f), h1 = fmaf(-2.0f, t1, 1.0f);
    float h2 = fmaf(-2.0f, t2, 1.0f), h3 = fmaf(-2.0f, t3, 1.0f);
    wlo = cvt_pk_bf16(h0, h1);
    whi = cvt_pk_bf16(h2, h3);
}

// sum_i w[i]*sigma(y[i]) with ONE rcp; no clamp (|y|<=~25 here)
__device__ __forceinline__ float quad_wsum_raw(float y0, float y1, float y2, float y3,
                                               float w0, float w1, float w2, float w3) {
    float d0 = 1.0f + __builtin_amdgcn_exp2f(y0);
    float d1 = 1.0f + __builtin_amdgcn_exp2f(y1);
    float d2 = 1.0f + __builtin_amdgcn_exp2f(y2);
    float d3 = 1.0f + __builtin_amdgcn_exp2f(y3);
    float Pab = d0 * d1, Pcd = d2 * d3;
    float R = __builtin_amdgcn_rcpf(Pab * Pcd);
    float N1 = fmaf(w1, d0, w0 * d1);
    float N2 = fmaf(w3, d2, w2 * d3);
    return fmaf(N2, Pab, N1 * Pcd) * R;
}

// layer2 MFMA + sigma-folded dot, sequential blocks (16 C regs live).
// Combined A: ET rows 0-15 (BASE=0), Q rows 16-31 (BASE=8).
template <int BASE>
__device__ __forceinline__ float tail_seq(const FragU a2,
    const float* __restrict__ b2, const float* __restrict__ w3,
    float pinit, bool hi, const FragU ba, const FragU bb)
{
    float w3s[8];
#pragma unroll
    for (int r = 0; r < 8; ++r) {
        const int j0 = (r & 3) + 8 * (r >> 2);
        w3s[r] = hi ? w3[j0 + 4] : w3[j0];
    }
    float p0, p1;
    {
        f32x16 c;
#pragma unroll
        for (int r = 0; r < 8; ++r) {
            const int j0 = (r & 3) + 8 * (r >> 2);
            c[BASE + r] = TWO_L2E * (hi ? b2[j0 + 4] : b2[j0]);
        }
        c = __builtin_amdgcn_mfma_f32_32x32x16_bf16(a2.f, ba.f, c, 0, 0, 0);
        float q = quad_wsum_raw(c[BASE + 0], c[BASE + 1], c[BASE + 2], c[BASE + 3],
                                w3s[0], w3s[1], w3s[2], w3s[3])
                + quad_wsum_raw(c[BASE + 4], c[BASE + 5], c[BASE + 6], c[BASE + 7],
                                w3s[4], w3s[5], w3s[6], w3s[7]);
        p0 = fmaf(-2.0f * L2E, q, pinit);
    }
    {
        f32x16 c;
#pragma unroll
        for (int r = 0; r < 8; ++r) {
            const int j0 = (r & 3) + 8 * (r >> 2);
            c[BASE + r] = TWO_L2E * (hi ? b2[j0 + 4] : b2[j0]);
        }
        c = __builtin_amdgcn_mfma_f32_32x32x16_bf16(a2.f, bb.f, c, 0, 0, 0);
        float q = quad_wsum_raw(c[BASE + 0], c[BASE + 1], c[BASE + 2], c[BASE + 3],
                                w3s[0], w3s[1], w3s[2], w3s[3])
                + quad_wsum_raw(c[BASE + 4], c[BASE + 5], c[BASE + 6], c[BASE + 7],
                                w3s[4], w3s[5], w3s[6], w3s[7]);
        p1 = fmaf(-2.0f * L2E, q, pinit);
    }
    return plswap_add(p0, p1);
}

#define SPT 2   // samples per thread (grid-stride, loop NOT unrolled)

__global__ __launch_bounds__(256, 8) void hydro_kernel(
    const float* __restrict__ g_t,
    const float* __restrict__ g_S,
    const float* __restrict__ g_precp,
    const float* __restrict__ g_temp,
    const float* __restrict__ g_lday,
    const float* __restrict__ g_ew1, const float* __restrict__ g_eb1,
    const float* __restrict__ g_ew2, const float* __restrict__ g_eb2,
    const float* __restrict__ g_ew3, const float* __restrict__ g_eb3,
    const float* __restrict__ g_qw1, const float* __restrict__ g_qb1,
    const float* __restrict__ g_qw2, const float* __restrict__ g_qb2,
    const float* __restrict__ g_qw3, const float* __restrict__ g_qb3,
    const float* __restrict__ g_Df, const float* __restrict__ g_Tmax,
    const float* __restrict__ g_Tmin,
    float* __restrict__ g_out, int B, int stride)
{
    const int tx = threadIdx.x;
    const int lane = tx & 63;
    const int m  = lane & 31;           // A row: <16 -> ET feature m, >=16 -> Q feature m-16
    const bool hi = (lane >> 5) != 0;   // k-group / C-row-half select

    // ---- one-time per-wave setup (amortized over SPT samples) ----
    FragU a2;
    {
        const float* wsrc = (m < 16) ? g_ew2 : g_qw2;
        const int mm = m & 15;
        const int kg8 = hi ? 8 : 0;
#pragma unroll
        for (int p = 0; p < 4; ++p) {
            const int k0 = kg8 + 2 * p, k1 = k0 + 1;
            a2.u[p] = cvt_pk_bf16(TWO_L2E * wsrc[k0 * 16 + mm],
                                  TWO_L2E * wsrc[k1 * 16 + mm]);
        }
    }
    float slo_e = 0.0f, shi_e = 0.0f, slo_q = 0.0f, shi_q = 0.0f;
#pragma unroll
    for (int r = 0; r < 8; ++r) {
        const int j0 = (r & 3) + 8 * (r >> 2);
        slo_e += g_ew3[j0]; shi_e += g_ew3[j0 + 4];
        slo_q += g_qw3[j0]; shi_q += g_qw3[j0 + 4];
    }
    const float pinit_e = L2E * fmaf(0.5f, g_eb3[0], hi ? shi_e : slo_e);
    const float pinit_q = L2E * fmaf(0.5f, g_qb3[0], hi ? shi_q : slo_q);

    const float Df   = fminf(fmaxf(g_Df[0],   0.01f), 5.0f);
    const float Tmax = fminf(fmaxf(g_Tmax[0], 0.0f),  3.0f);
    const float Tmin = fminf(fmaxf(g_Tmin[0], -3.0f), 0.0f);

    const int base = blockIdx.x * 256 + tx;

#pragma unroll 1
    for (int s = 0; s < SPT; ++s) {
        const int i = base + s * stride;
        const int ic = (i < B) ? i : (B - 1);   // all lanes stay active for cross-lane ops

        const float tv = g_t[ic];
        const float2 Sv = reinterpret_cast<const float2*>(g_S)[ic];
        const float S_snow = Sv.x, S_water = Sv.y;

        int idx = (int)tv;
        idx = max(0, min(idx, TLEN - 2));
        const float fr = tv - (float)idx;
        const float p0v = g_precp[idx], p1v = g_precp[idx + 1];
        const float t0v = g_temp[idx],  t1v = g_temp[idx + 1];
        const float l0v = g_lday[idx],  l1v = g_lday[idx + 1];
        const float precp = fmaf(fr, p1v - p0v, p0v);
        const float temp  = fmaf(fr, t1v - t0v, t0v);
        const float lday  = fmaf(fr, l1v - l0v, l0v);

        // ===== ET: layer1 -> pack -> MFMA tail =====
        float ETs;
        {
            unsigned w[8];
#pragma unroll
            for (int j4 = 0; j4 < 4; ++j4) {
                float4 b4 = *reinterpret_cast<const float4*>(&g_eb1[j4 * 4]);
                float4 w0 = *reinterpret_cast<const float4*>(&g_ew1[0 * 16 + j4 * 4]);
                float4 w1 = *reinterpret_cast<const float4*>(&g_ew1[1 * 16 + j4 * 4]);
                float4 w2 = *reinterpret_cast<const float4*>(&g_ew1[2 * 16 + j4 * 4]);
                float y0 = TWO_L2E * fmaf(temp, w2.x, fmaf(S_water, w1.x, fmaf(S_snow, w0.x, b4.x)));
                float y1 = TWO_L2E * fmaf(temp, w2.y, fmaf(S_water, w1.y, fmaf(S_snow, w0.y, b4.y)));
                float y2 = TWO_L2E * fmaf(temp, w2.z, fmaf(S_water, w1.z, fmaf(S_snow, w0.z, b4.z)));
                float y3 = TWO_L2E * fmaf(temp, w2.w, fmaf(S_water, w1.w, fmaf(S_snow, w0.w, b4.w)));
                unsigned wl, wh;
                quad_tanh_pack(y0, y1, y2, y3, wl, wh);
                w[2 * j4]     = wl;
                w[2 * j4 + 1] = wh;
            }
            FragU ba, bb;
#pragma unroll
            for (int p = 0; p < 4; ++p) {
                unsigned a = w[p], b = w[p + 4];
                plswap(a, b);
                ba.u[p] = a; bb.u[p] = b;
            }
            ETs = tail_seq<0>(a2, g_eb2, g_ew3, pinit_e, hi, ba, bb);
        }

        // ===== Q: layer1 -> pack -> MFMA tail =====
        float Qs;
        {
            unsigned w[8];
#pragma unroll
            for (int j4 = 0; j4 < 4; ++j4) {
                float4 b4 = *reinterpret_cast<const float4*>(&g_qb1[j4 * 4]);
                float4 w0 = *reinterpret_cast<const float4*>(&g_qw1[0 * 16 + j4 * 4]);
                float4 w1 = *reinterpret_cast<const float4*>(&g_qw1[1 * 16 + j4 * 4]);
                float y0 = TWO_L2E * fmaf(precp, w1.x, fmaf(S_water, w0.x, b4.x));
                float y1 = TWO_L2E * fmaf(precp, w1.y, fmaf(S_water, w0.y, b4.y));
                float y2 = TWO_L2E * fmaf(precp, w1.z, fmaf(S_water, w0.z, b4.z));
                float y3 = TWO_L2E * fmaf(precp, w1.w, fmaf(S_water, w0.w, b4.w));
                unsigned wl, wh;
                quad_tanh_pack(y0, y1, y2, y3, wl, wh);
                w[2 * j4]     = wl;
                w[2 * j4 + 1] = wh;
            }
            FragU ba, bb;
#pragma unroll
            for (int p = 0; p < 4; ++p) {
                unsigned a = w[p], b = w[p + 4];
                plswap(a, b);
                ba.u[p] = a; bb.u[p] = b;
            }
            Qs = tail_seq<8>(a2, g_qb2, g_qw3, pinit_q, hi, ba, bb);
        }

        // ===== bucket dynamics: 4 steps share ONE rcp =====
        float ya = fminf(fmaxf(NL2E10 * S_water,       -31.0f), 31.0f);
        float yb = fminf(fmaxf(NL2E10 * (temp - Tmin), -31.0f), 31.0f);
        float yc = fminf(fmaxf(NL2E10 * (temp - Tmax), -31.0f), 31.0f);
        float yd = fminf(fmaxf(NL2E10 * S_snow,        -31.0f), 31.0f);
        float da = 1.0f + __builtin_amdgcn_exp2f(ya);
        float db = 1.0f + __builtin_amdgcn_exp2f(yb);
        float dc = 1.0f + __builtin_amdgcn_exp2f(yc);
        float dd = 1.0f + __builtin_amdgcn_exp2f(yd);
        float Pab = da * db, Pcd = dc * dd;
        float R = __builtin_amdgcn_rcpf(Pab * Pcd);
        float RPcd = Pcd * R, RPab = Pab * R;
        const float sw_step = db * RPcd;
        const float sp      = da * RPcd;
        const float st_tmax = dd * RPab;
        const float st_snow = dc * RPab;

        const float melt = st_tmax * st_snow * fminf(S_snow, Df * (temp - Tmax));
        const float dS1 = (1.0f - sp) * precp - melt;
        const float dS2 = sp * precp + melt
                        - sw_step * fmaf(lday, __builtin_amdgcn_exp2f(ETs),
                                         __builtin_amdgcn_exp2f(Qs));

        if (i < B) {
            reinterpret_cast<float2*>(g_out)[i] = make_float2(dS1, dS2);
        }
    }
}

extern "C" void kernel_launch(void* const* d_in, const int* in_sizes, int n_in,
                              void* d_out, int out_size, void* d_ws, size_t ws_size,
                              hipStream_t stream)
{
    const int B = in_sizes[0];
    const int block = 256;
    const int grid = (B + block * SPT - 1) / (block * SPT);
    const int stride = grid * block;
    hipLaunchKernelGGL(hydro_kernel, dim3(grid), dim3(block), 0, stream,
        (const float*)d_in[0],  // t
        (const float*)d_in[1],  // S
        (const float*)d_in[3],  // precp_series
        (const float*)d_in[4],  // temp_series
        (const float*)d_in[5],  // lday_series
        (const float*)d_in[6],  (const float*)d_in[7],
        (const float*)d_in[8],  (const float*)d_in[9],
        (const float*)d_in[10], (const float*)d_in[11],
        (const float*)d_in[12], (const float*)d_in[13],
        (const float*)d_in[14], (const float*)d_in[15],
        (const float*)d_in[16], (const float*)d_in[17],
        (const float*)d_in[21], // Df
        (const float*)d_in[22], // Tmax
        (const float*)d_in[23], // Tmin
        (float*)d_out, B, stride);
}

// Round 16
// 26.382 us; speedup vs baseline: 3.2093x; 1.2073x over previous
//
#include <hip/hip_runtime.h>

#define TLEN 1461
#define L2E      1.44269504088896340736f
#define TWO_L2E  2.88539008177792681472f
#define NL2E10  -14.4269504088896341f

typedef __bf16 bf16x8 __attribute__((ext_vector_type(8)));
typedef float f32x16 __attribute__((ext_vector_type(16)));

union FragU { unsigned u[4]; bf16x8 f; };

__device__ __forceinline__ unsigned cvt_pk_bf16(float lo, float hi) {
    unsigned r;
    asm("v_cvt_pk_bf16_f32 %0, %1, %2" : "=v"(r) : "v"(lo), "v"(hi));
    return r;
}
__device__ __forceinline__ void plswap(unsigned &a, unsigned &b) {
    asm("v_permlane32_swap_b32 %0, %1" : "+v"(a), "+v"(b));
}
__device__ __forceinline__ float plswap_add(float a, float b) {
    unsigned ua = __float_as_uint(a), ub = __float_as_uint(b);
    plswap(ua, ub);
    return __uint_as_float(ua) + __uint_as_float(ub);
}

// 4 pre-activations y=2*log2e*x -> tanh, ONE rcp per 4 (clamp +-30)
__device__ __forceinline__ void quad_tanh_pack(float y0, float y1, float y2, float y3,
                                               unsigned &wlo, unsigned &whi) {
    y0 = fminf(fmaxf(y0, -30.0f), 30.0f);
    y1 = fminf(fmaxf(y1, -30.0f), 30.0f);
    y2 = fminf(fmaxf(y2, -30.0f), 30.0f);
    y3 = fminf(fmaxf(y3, -30.0f), 30.0f);
    float d0 = 1.0f + __builtin_amdgcn_exp2f(y0);
    float d1 = 1.0f + __builtin_amdgcn_exp2f(y1);
    float d2 = 1.0f + __builtin_amdgcn_exp2f(y2);
    float d3 = 1.0f + __builtin_amdgcn_exp2f(y3);
    float Pab = d0 * d1, Pcd = d2 * d3;
    float R = __builtin_amdgcn_rcpf(Pab * Pcd);
    float RPcd = Pcd * R;   // = 1/(d0 d1)
    float RPab = Pab * R;   // = 1/(d2 d3)
    float t0 = d1 * RPcd, t1 = d0 * RPcd;
    float t2 = d3 * RPab, t3 = d2 * RPab;
    float h0 = fmaf(-2.0f, t0, 1.0f), h1 = fmaf(-2.0f, t1, 1.0f);
    float h2 = fmaf(-2.0f, t2, 1.0f), h3 = fmaf(-2.0f, t3, 1.0f);
    wlo = cvt_pk_bf16(h0, h1);
    whi = cvt_pk_bf16(h2, h3);
}

// sum_i w[i]*sigma(y[i]) with ONE rcp; no clamp (|y|<=~25 here)
__device__ __forceinline__ float quad_wsum_raw(float y0, float y1, float y2, float y3,
                                               float w0, float w1, float w2, float w3) {
    float d0 = 1.0f + __builtin_amdgcn_exp2f(y0);
    float d1 = 1.0f + __builtin_amdgcn_exp2f(y1);
    float d2 = 1.0f + __builtin_amdgcn_exp2f(y2);
    float d3 = 1.0f + __builtin_amdgcn_exp2f(y3);
    float Pab = d0 * d1, Pcd = d2 * d3;
    float R = __builtin_amdgcn_rcpf(Pab * Pcd);
    float N1 = fmaf(w1, d0, w0 * d1);
    float N2 = fmaf(w3, d2, w2 * d3);
    return fmaf(N2, Pab, N1 * Pcd) * R;
}

// layer2 MFMA + sigma-folded dot, sequential blocks (16 C regs live).
// Combined A: ET rows 0-15 (BASE=0), Q rows 16-31 (BASE=8).
template <int BASE>
__device__ __forceinline__ float tail_seq(const FragU a2,
    const float* __restrict__ b2, const float* __restrict__ w3,
    float pinit, bool hi, const FragU ba, const FragU bb)
{
    float w3s[8];
#pragma unroll
    for (int r = 0; r < 8; ++r) {
        const int j0 = (r & 3) + 8 * (r >> 2);
        w3s[r] = hi ? w3[j0 + 4] : w3[j0];
    }
    float p0, p1;
    {
        f32x16 c;
#pragma unroll
        for (int r = 0; r < 8; ++r) {
            const int j0 = (r & 3) + 8 * (r >> 2);
            c[BASE + r] = TWO_L2E * (hi ? b2[j0 + 4] : b2[j0]);
        }
        c = __builtin_amdgcn_mfma_f32_32x32x16_bf16(a2.f, ba.f, c, 0, 0, 0);
        float q = quad_wsum_raw(c[BASE + 0], c[BASE + 1], c[BASE + 2], c[BASE + 3],
                                w3s[0], w3s[1], w3s[2], w3s[3])
                + quad_wsum_raw(c[BASE + 4], c[BASE + 5], c[BASE + 6], c[BASE + 7],
                                w3s[4], w3s[5], w3s[6], w3s[7]);
        p0 = fmaf(-2.0f * L2E, q, pinit);
    }
    {
        f32x16 c;
#pragma unroll
        for (int r = 0; r < 8; ++r) {
            const int j0 = (r & 3) + 8 * (r >> 2);
            c[BASE + r] = TWO_L2E * (hi ? b2[j0 + 4] : b2[j0]);
        }
        c = __builtin_amdgcn_mfma_f32_32x32x16_bf16(a2.f, bb.f, c, 0, 0, 0);
        float q = quad_wsum_raw(c[BASE + 0], c[BASE + 1], c[BASE + 2], c[BASE + 3],
                                w3s[0], w3s[1], w3s[2], w3s[3])
                + quad_wsum_raw(c[BASE + 4], c[BASE + 5], c[BASE + 6], c[BASE + 7],
                                w3s[4], w3s[5], w3s[6], w3s[7]);
        p1 = fmaf(-2.0f * L2E, q, pinit);
    }
    return plswap_add(p0, p1);
}

__global__ __launch_bounds__(256, 8) void hydro_kernel(
    const float* __restrict__ g_t,
    const float* __restrict__ g_S,
    const float* __restrict__ g_precp,
    const float* __restrict__ g_temp,
    const float* __restrict__ g_lday,
    const float* __restrict__ g_ew1, const float* __restrict__ g_eb1,
    const float* __restrict__ g_ew2, const float* __restrict__ g_eb2,
    const float* __restrict__ g_ew3, const float* __restrict__ g_eb3,
    const float* __restrict__ g_qw1, const float* __restrict__ g_qb1,
    const float* __restrict__ g_qw2, const float* __restrict__ g_qb2,
    const float* __restrict__ g_qw3, const float* __restrict__ g_qb3,
    const float* __restrict__ g_Df, const float* __restrict__ g_Tmax,
    const float* __restrict__ g_Tmin,
    float* __restrict__ g_out, int B)
{
    const int tx = threadIdx.x;
    const int lane = tx & 63;
    const int m  = lane & 31;           // A row: <16 -> ET feature m, >=16 -> Q feature m-16
    const bool hi = (lane >> 5) != 0;   // k-group / C-row-half select

    // combined A-fragment (4 VGPRs): ET W2 rows 0-15, Q W2 rows 16-31
    FragU a2;
    {
        const float* wsrc = (m < 16) ? g_ew2 : g_qw2;
        const int mm = m & 15;
        const int kg8 = hi ? 8 : 0;
#pragma unroll
        for (int p = 0; p < 4; ++p) {
            const int k0 = kg8 + 2 * p, k1 = k0 + 1;
            a2.u[p] = cvt_pk_bf16(TWO_L2E * wsrc[k0 * 16 + mm],
                                  TWO_L2E * wsrc[k1 * 16 + mm]);
        }
    }

    // pinit = l2e*(0.5*b3 + sum8(w3 rows of this half))
    float slo_e = 0.0f, shi_e = 0.0f, slo_q = 0.0f, shi_q = 0.0f;
#pragma unroll
    for (int r = 0; r < 8; ++r) {
        const int j0 = (r & 3) + 8 * (r >> 2);
        slo_e += g_ew3[j0]; shi_e += g_ew3[j0 + 4];
        slo_q += g_qw3[j0]; shi_q += g_qw3[j0 + 4];
    }
    const float pinit_e = L2E * fmaf(0.5f, g_eb3[0], hi ? shi_e : slo_e);
    const float pinit_q = L2E * fmaf(0.5f, g_qb3[0], hi ? shi_q : slo_q);

    const float Df   = fminf(fmaxf(g_Df[0],   0.01f), 5.0f);
    const float Tmax = fminf(fmaxf(g_Tmax[0], 0.0f),  3.0f);
    const float Tmin = fminf(fmaxf(g_Tmin[0], -3.0f), 0.0f);

    // ONE sample per thread
    const int i = blockIdx.x * 256 + tx;
    const int ic = (i < B) ? i : (B - 1);   // all lanes stay active for cross-lane ops

    const float tv = g_t[ic];
    const float2 Sv = reinterpret_cast<const float2*>(g_S)[ic];
    const float S_snow = Sv.x, S_water = Sv.y;

    int idx = (int)tv;
    idx = max(0, min(idx, TLEN - 2));
    const float fr = tv - (float)idx;
    // per-lane global gathers, L1-resident after warmup
    const float p0v = g_precp[idx], p1v = g_precp[idx + 1];
    const float t0v = g_temp[idx],  t1v = g_temp[idx + 1];
    const float l0v = g_lday[idx],  l1v = g_lday[idx + 1];
    const float precp = fmaf(fr, p1v - p0v, p0v);
    const float temp  = fmaf(fr, t1v - t0v, t0v);
    const float lday  = fmaf(fr, l1v - l0v, l0v);

    // ===== ET: layer1 -> pack -> MFMA tail =====
    float ETs;
    {
        unsigned w[8];
#pragma unroll
        for (int j4 = 0; j4 < 4; ++j4) {
            float4 b4 = *reinterpret_cast<const float4*>(&g_eb1[j4 * 4]);
            float4 w0 = *reinterpret_cast<const float4*>(&g_ew1[0 * 16 + j4 * 4]);
            float4 w1 = *reinterpret_cast<const float4*>(&g_ew1[1 * 16 + j4 * 4]);
            float4 w2 = *reinterpret_cast<const float4*>(&g_ew1[2 * 16 + j4 * 4]);
            float y0 = TWO_L2E * fmaf(temp, w2.x, fmaf(S_water, w1.x, fmaf(S_snow, w0.x, b4.x)));
            float y1 = TWO_L2E * fmaf(temp, w2.y, fmaf(S_water, w1.y, fmaf(S_snow, w0.y, b4.y)));
            float y2 = TWO_L2E * fmaf(temp, w2.z, fmaf(S_water, w1.z, fmaf(S_snow, w0.z, b4.z)));
            float y3 = TWO_L2E * fmaf(temp, w2.w, fmaf(S_water, w1.w, fmaf(S_snow, w0.w, b4.w)));
            unsigned wl, wh;
            quad_tanh_pack(y0, y1, y2, y3, wl, wh);
            w[2 * j4]     = wl;
            w[2 * j4 + 1] = wh;
        }
        FragU ba, bb;
#pragma unroll
        for (int p = 0; p < 4; ++p) {
            unsigned a = w[p], b = w[p + 4];
            plswap(a, b);
            ba.u[p] = a; bb.u[p] = b;
        }
        ETs = tail_seq<0>(a2, g_eb2, g_ew3, pinit_e, hi, ba, bb);
    }

    // ===== Q: layer1 -> pack -> MFMA tail =====
    float Qs;
    {
        unsigned w[8];
#pragma unroll
        for (int j4 = 0; j4 < 4; ++j4) {
            float4 b4 = *reinterpret_cast<const float4*>(&g_qb1[j4 * 4]);
            float4 w0 = *reinterpret_cast<const float4*>(&g_qw1[0 * 16 + j4 * 4]);
            float4 w1 = *reinterpret_cast<const float4*>(&g_qw1[1 * 16 + j4 * 4]);
            float y0 = TWO_L2E * fmaf(precp, w1.x, fmaf(S_water, w0.x, b4.x));
            float y1 = TWO_L2E * fmaf(precp, w1.y, fmaf(S_water, w0.y, b4.y));
            float y2 = TWO_L2E * fmaf(precp, w1.z, fmaf(S_water, w0.z, b4.z));
            float y3 = TWO_L2E * fmaf(precp, w1.w, fmaf(S_water, w0.w, b4.w));
            unsigned wl, wh;
            quad_tanh_pack(y0, y1, y2, y3, wl, wh);
            w[2 * j4]     = wl;
            w[2 * j4 + 1] = wh;
        }
        FragU ba, bb;
#pragma unroll
        for (int p = 0; p < 4; ++p) {
            unsigned a = w[p], b = w[p + 4];
            plswap(a, b);
            ba.u[p] = a; bb.u[p] = b;
        }
        Qs = tail_seq<8>(a2, g_qb2, g_qw3, pinit_q, hi, ba, bb);
    }

    // ===== bucket dynamics: 4 steps share ONE rcp (clamp +-31 keeps product finite) =====
    float ya = fminf(fmaxf(NL2E10 * S_water,       -31.0f), 31.0f);
    float yb = fminf(fmaxf(NL2E10 * (temp - Tmin), -31.0f), 31.0f);
    float yc = fminf(fmaxf(NL2E10 * (temp - Tmax), -31.0f), 31.0f);
    float yd = fminf(fmaxf(NL2E10 * S_snow,        -31.0f), 31.0f);
    float da = 1.0f + __builtin_amdgcn_exp2f(ya);
    float db = 1.0f + __builtin_amdgcn_exp2f(yb);
    float dc = 1.0f + __builtin_amdgcn_exp2f(yc);
    float dd = 1.0f + __builtin_amdgcn_exp2f(yd);
    float Pab = da * db, Pcd = dc * dd;
    float R = __builtin_amdgcn_rcpf(Pab * Pcd);
    float RPcd = Pcd * R, RPab = Pab * R;
    const float sw_step = db * RPcd;   // sigma = 1/da
    const float sp      = da * RPcd;   // step(temp - Tmin)
    const float st_tmax = dd * RPab;   // step(temp - Tmax)
    const float st_snow = dc * RPab;   // step(S_snow)

    const float melt = st_tmax * st_snow * fminf(S_snow, Df * (temp - Tmax));
    const float dS1 = (1.0f - sp) * precp - melt;
    const float dS2 = sp * precp + melt
                    - sw_step * fmaf(lday, __builtin_amdgcn_exp2f(ETs),
                                     __builtin_amdgcn_exp2f(Qs));

    if (i < B) {
        reinterpret_cast<float2*>(g_out)[i] = make_float2(dS1, dS2);
    }
}

extern "C" void kernel_launch(void* const* d_in, const int* in_sizes, int n_in,
                              void* d_out, int out_size, void* d_ws, size_t ws_size,
                              hipStream_t stream)
{
    const int B = in_sizes[0];
    const int block = 256;
    const int grid = (B + block - 1) / block;
    hipLaunchKernelGGL(hydro_kernel, dim3(grid), dim3(block), 0, stream,
        (const float*)d_in[0],  // t
        (const float*)d_in[1],  // S
        (const float*)d_in[3],  // precp_series
        (const float*)d_in[4],  // temp_series
        (const float*)d_in[5],  // lday_series
        (const float*)d_in[6],  (const float*)d_in[7],
        (const float*)d_in[8],  (const float*)d_in[9],
        (const float*)d_in[10], (const float*)d_in[11],
        (const float*)d_in[12], (const float*)d_in[13],
        (const float*)d_in[14], (const float*)d_in[15],
        (const float*)d_in[16], (const float*)d_in[17],
        (const float*)d_in[21], // Df
        (const float*)d_in[22], // Tmax
        (const float*)d_in[23], // Tmin
        (float*)d_out, B);
}